// Round 1
// baseline (943.405 us; speedup 1.0000x reference)
//
#include <hip/hip_runtime.h>
#include <hip/hip_bf16.h>

#define NNODES 100000
#define NEDGES 1600000
#define NRELS 16
#define NBASES 8
#define DFEAT 128
#define NCLS 40
#define MAXDEG 64
#define KTOT 1152   // NBASES*128 + 128 (root)

typedef __attribute__((ext_vector_type(8))) short bf16x8v;
typedef __attribute__((ext_vector_type(4))) float f32x4v;

__global__ __launch_bounds__(256)
void k_convert(const float* __restrict__ x, __hip_bfloat16* __restrict__ xb, int n)
{
    int i = blockIdx.x * 256 + threadIdx.x;
    if (i < n) xb[i] = __float2bfloat16(x[i]);
}

// One pass: per-(dst,rel) degree (for norm), per-dst degree, and ELL scatter.
// atomicAdd's return value IS the ELL slot -> no sort, no scan.
__global__ __launch_bounds__(256)
void k_build(const int* __restrict__ esrc, const int* __restrict__ edst,
             const int* __restrict__ etyp,
             unsigned* __restrict__ degD, unsigned* __restrict__ degDT,
             unsigned* __restrict__ ell)
{
    int e = blockIdx.x * 256 + threadIdx.x;
    if (e >= NEDGES) return;
    int d = edst[e], t = etyp[e], s = esrc[e];
    atomicAdd(&degDT[d * NRELS + t], 1u);
    unsigned slot = atomicAdd(&degD[d], 1u);
    if (slot < MAXDEG) ell[(size_t)d * MAXDEG + slot] = ((unsigned)s << 4) | (unsigned)t;
}

// Per dst node: g[b,:] = sum_e comp[type_e,b] * (1/deg(dst,type_e)) * x[src_e,:]
// One wave per node, lane owns 2 feature channels (bf16x2). Writes one row of
// A = [g(8*128) | x(128)] in bf16, ready for the MFMA GEMM.
__global__ __launch_bounds__(256)
void k_agg(const __hip_bfloat16* __restrict__ hin,
           const unsigned* __restrict__ ell,
           const unsigned* __restrict__ degD,
           const unsigned* __restrict__ degDT,
           const float* __restrict__ comp,
           __hip_bfloat16* __restrict__ A,
           int r0, int rows)
{
    __shared__ float compS[NRELS * NBASES];
    if (threadIdx.x < NRELS * NBASES) compS[threadIdx.x] = comp[threadIdx.x];
    __syncthreads();
    int wave = threadIdx.x >> 6, lane = threadIdx.x & 63;
    int rl = blockIdx.x * 4 + wave;
    if (rl >= rows) return;
    int v = r0 + rl;
    int ne = (int)degD[v]; if (ne > MAXDEG) ne = MAXDEG;
    float accx[NBASES], accy[NBASES];
#pragma unroll
    for (int b = 0; b < NBASES; b++) { accx[b] = 0.f; accy[b] = 0.f; }
    const __hip_bfloat162* h2p = (const __hip_bfloat162*)hin;
    const unsigned* erow = ell + (size_t)v * MAXDEG;
    const unsigned* drow = degDT + v * NRELS;
    for (int e = 0; e < ne; e++) {
        unsigned ed = erow[e];
        int t = (int)(ed & 15u);
        int s = (int)(ed >> 4);
        float norm = 1.0f / (float)drow[t];   // deg>=1 guaranteed for present edge
        __hip_bfloat162 xv = h2p[s * 64 + lane];
        float xl = __bfloat162float(xv.x), xh = __bfloat162float(xv.y);
#pragma unroll
        for (int b = 0; b < NBASES; b++) {
            float sc = compS[t * NBASES + b] * norm;
            accx[b] += sc * xl;
            accy[b] += sc * xh;
        }
    }
    __hip_bfloat162* A2 = (__hip_bfloat162*)(A + (size_t)rl * KTOT);
#pragma unroll
    for (int b = 0; b < NBASES; b++) {
        __hip_bfloat162 o;
        o.x = __float2bfloat16(accx[b]);
        o.y = __float2bfloat16(accy[b]);
        A2[b * 64 + lane] = o;
    }
    A2[512 + lane] = h2p[(size_t)v * 64 + lane];   // root part: own features
}

// WT[o][k] (B^T, K-contiguous): k<1024 -> bases[b=k>>7][i=k&127][o] = bases[k*dout+o]
//                               k>=1024 -> root[k-1024][o].  Rows o>=dout zero-padded.
__global__ __launch_bounds__(256)
void k_w(const float* __restrict__ bases, const float* __restrict__ root,
         __hip_bfloat16* __restrict__ WT, int dout, int npad)
{
    int idx = blockIdx.x * 256 + threadIdx.x;
    int total = npad * KTOT;
    if (idx >= total) return;
    int o = idx / KTOT, k = idx - o * KTOT;
    float v = 0.f;
    if (o < dout) v = (k < 1024) ? bases[k * dout + o] : root[(k - 1024) * dout + o];
    WT[idx] = __float2bfloat16(v);
}

// C[M,NT] = A[M,K] * WT[NT,K]^T, 128x{128|64} block tile, BK=32, 4 waves,
// mfma_f32_16x16x32_bf16. A-frag: m=lane&15, k=(lane>>4)*8+j (ds_read_b128).
// C/D: col=lane&15, row=(lane>>4)*4+reg.
template<int NT, bool RELU, bool FINAL>
__global__ __launch_bounds__(256)
void k_gemm(const __hip_bfloat16* __restrict__ A,
            const __hip_bfloat16* __restrict__ WT,
            const float* __restrict__ bias,
            void* __restrict__ outp,
            int r0, int rows, int dout)
{
    constexpr int WM = (NT == 128) ? 2 : 4;   // waves along M
    constexpr int WN = 4 / WM;                // waves along N
    constexpr int MT = 128 / (16 * WM);       // 16-row subtiles per wave
    constexpr int NTW = NT / (16 * WN);       // 16-col subtiles per wave
    __shared__ __align__(16) __hip_bfloat16 As[128 * 32];
    __shared__ __align__(16) __hip_bfloat16 Bs[NT * 32];
    int tid = threadIdx.x;
    int wave = tid >> 6, lane = tid & 63;
    int wm = wave % WM, wn = wave / WM;
    int bm = blockIdx.x * 128;
    int lm = lane & 15, lq = lane >> 4;
    f32x4v zero = {0.f, 0.f, 0.f, 0.f};
    f32x4v acc[MT][NTW];
#pragma unroll
    for (int a = 0; a < MT; a++)
#pragma unroll
        for (int b = 0; b < NTW; b++) acc[a][b] = zero;

    for (int k0 = 0; k0 < KTOT; k0 += 32) {
#pragma unroll
        for (int j = 0; j < 2; j++) {          // stage A tile: 128x32 bf16
            int slot = tid + 256 * j;
            int row = slot >> 2, kc = (slot & 3) << 3;
            *(int4*)&As[row * 32 + kc] =
                *(const int4*)&A[(size_t)(bm + row) * KTOT + k0 + kc];
        }
#pragma unroll
        for (int j = 0; j < NT / 64; j++) {    // stage B tile: NTx32 bf16
            int slot = tid + 256 * j;
            int row = slot >> 2, kc = (slot & 3) << 3;
            *(int4*)&Bs[row * 32 + kc] =
                *(const int4*)&WT[(size_t)row * KTOT + k0 + kc];
        }
        __syncthreads();
        bf16x8v af[MT], bfr[NTW];
#pragma unroll
        for (int mt = 0; mt < MT; mt++)
            af[mt] = *(const bf16x8v*)&As[(wm * (16 * MT) + mt * 16 + lm) * 32 + lq * 8];
#pragma unroll
        for (int nt = 0; nt < NTW; nt++)
            bfr[nt] = *(const bf16x8v*)&Bs[(wn * (16 * NTW) + nt * 16 + lm) * 32 + lq * 8];
#pragma unroll
        for (int mt = 0; mt < MT; mt++)
#pragma unroll
            for (int nt = 0; nt < NTW; nt++)
                acc[mt][nt] = __builtin_amdgcn_mfma_f32_16x16x32_bf16(
                    af[mt], bfr[nt], acc[mt][nt], 0, 0, 0);
        __syncthreads();
    }
#pragma unroll
    for (int mt = 0; mt < MT; mt++) {
        int rbase = bm + wm * (16 * MT) + mt * 16 + lq * 4;
#pragma unroll
        for (int nt = 0; nt < NTW; nt++) {
            int col = wn * (16 * NTW) + nt * 16 + lm;
#pragma unroll
            for (int i = 0; i < 4; i++) {
                int rl = rbase + i;
                if (rl < rows && col < dout) {
                    float v = acc[mt][nt][i] + bias[col];
                    if (RELU) v = fmaxf(v, 0.f);
                    if (FINAL)
                        ((float*)outp)[(size_t)(r0 + rl) * NCLS + col] = v;
                    else
                        ((__hip_bfloat16*)outp)[(size_t)(r0 + rl) * DFEAT + col] =
                            __float2bfloat16(v);
                }
            }
        }
    }
}

extern "C" void kernel_launch(void* const* d_in, const int* in_sizes, int n_in,
                              void* d_out, int out_size, void* d_ws, size_t ws_size,
                              hipStream_t stream)
{
    const float* x  = (const float*)d_in[0];
    const int* esrc = (const int*)d_in[1];
    const int* edst = (const int*)d_in[2];
    const int* etyp = (const int*)d_in[3];
    const float* basesA[3] = {(const float*)d_in[4], (const float*)d_in[8], (const float*)d_in[12]};
    const float* compA[3]  = {(const float*)d_in[5], (const float*)d_in[9], (const float*)d_in[13]};
    const float* rootA[3]  = {(const float*)d_in[6], (const float*)d_in[10], (const float*)d_in[14]};
    const float* biasA[3]  = {(const float*)d_in[7], (const float*)d_in[11], (const float*)d_in[15]};

    size_t off = 0;
    char* base = (char*)d_ws;
    auto carve = [&](size_t bytes) -> void* {
        void* r = base + off;
        off += (bytes + 255) & ~(size_t)255;
        return r;
    };
    __hip_bfloat16* xb = (__hip_bfloat16*)carve((size_t)NNODES * DFEAT * 2);
    __hip_bfloat16* h1 = (__hip_bfloat16*)carve((size_t)NNODES * DFEAT * 2);
    __hip_bfloat16* h2 = (__hip_bfloat16*)carve((size_t)NNODES * DFEAT * 2);
    __hip_bfloat16* WT = (__hip_bfloat16*)carve((size_t)128 * KTOT * 2);
    unsigned* ell   = (unsigned*)carve((size_t)NNODES * MAXDEG * 4);
    unsigned* degD  = (unsigned*)carve((size_t)NNODES * 4);
    unsigned* degDT = (unsigned*)carve((size_t)NNODES * NRELS * 4);

    if (ws_size <= off) return;
    size_t arows = (ws_size - off) / ((size_t)KTOT * 2);
    if (arows > 100096) arows = 100096;        // 782*128
    int chunk = (int)(arows & ~(size_t)127);
    if (chunk < 128) return;                    // workspace too small -> visible fail
    __hip_bfloat16* A = (__hip_bfloat16*)(base + off);

    hipMemsetAsync(degD, 0, (size_t)NNODES * 4, stream);
    hipMemsetAsync(degDT, 0, (size_t)NNODES * NRELS * 4, stream);
    k_convert<<<(NNODES * DFEAT + 255) / 256, 256, 0, stream>>>(x, xb, NNODES * DFEAT);
    k_build<<<(NEDGES + 255) / 256, 256, 0, stream>>>(esrc, edst, etyp, degD, degDT, ell);

    const __hip_bfloat16* hin = xb;
    __hip_bfloat16* houts[2] = {h1, h2};
    for (int l = 0; l < 3; l++) {
        int dout = (l == 2) ? NCLS : DFEAT;
        int npad = (l == 2) ? 64 : 128;
        k_w<<<(npad * KTOT + 255) / 256, 256, 0, stream>>>(basesA[l], rootA[l], WT, dout, npad);
        for (int r0 = 0; r0 < NNODES; r0 += chunk) {
            int rows = NNODES - r0; if (rows > chunk) rows = chunk;
            k_agg<<<(rows + 3) / 4, 256, 0, stream>>>(hin, ell, degD, degDT, compA[l], A, r0, rows);
            int gm = (rows + 127) / 128;
            if (l < 2)
                k_gemm<128, true, false><<<gm, 256, 0, stream>>>(A, WT, biasA[l], houts[l], r0, rows, dout);
            else
                k_gemm<64, false, true><<<gm, 256, 0, stream>>>(A, WT, biasA[l], d_out, r0, rows, dout);
        }
        if (l < 2) hin = houts[l];
    }
}

// Round 2
// 843.800 us; speedup vs baseline: 1.1180x; 1.1180x over previous
//
#include <hip/hip_runtime.h>
#include <hip/hip_bf16.h>

#define NNODES 100000
#define NEDGES 1600000
#define NRELS 16
#define NBASES 8
#define DFEAT 128
#define NCLS 40
#define MAXDEG 64
#define KTOT 1152   // NBASES*128 + 128 (root)

typedef __attribute__((ext_vector_type(8))) short bf16x8v;
typedef __attribute__((ext_vector_type(4))) float f32x4v;

__global__ __launch_bounds__(256)
void k_convert(const float* __restrict__ x, __hip_bfloat16* __restrict__ xb, int n)
{
    int i = blockIdx.x * 256 + threadIdx.x;
    if (i < n) xb[i] = __float2bfloat16(x[i]);
}

// One atomic per edge: degD slot-claim doubles as ELL write index.
// Per-(dst,rel) degree is recomputed cheaply in k_agg from the row itself.
__global__ __launch_bounds__(256)
void k_build(const int* __restrict__ esrc, const int* __restrict__ edst,
             const int* __restrict__ etyp,
             unsigned* __restrict__ degD, unsigned* __restrict__ ell)
{
    int e = blockIdx.x * 256 + threadIdx.x;
    if (e >= NEDGES) return;
    int d = edst[e], t = etyp[e], s = esrc[e];
    unsigned slot = atomicAdd(&degD[d], 1u);
    if (slot < MAXDEG) ell[(size_t)d * MAXDEG + slot] = ((unsigned)s << 4) | (unsigned)t;
}

// One wave per node. Lane e holds edge e (coalesced row load). Per-edge type
// counts via 4-bit ballot match (popcount). Edge loop broadcasts via
// __shfl(_, e) with wave-uniform e -> v_readlane -> scalar gather base.
__global__ __launch_bounds__(256)
void k_agg(const __hip_bfloat16* __restrict__ hin,
           const unsigned* __restrict__ ell,
           const unsigned* __restrict__ degD,
           const float* __restrict__ comp,
           __hip_bfloat16* __restrict__ A,
           int r0, int rows)
{
    __shared__ float compS[NRELS * NBASES];
    if (threadIdx.x < NRELS * NBASES) compS[threadIdx.x] = comp[threadIdx.x];
    __syncthreads();
    int wave = threadIdx.x >> 6, lane = threadIdx.x & 63;
    int rl = blockIdx.x * 4 + wave;
    if (rl >= rows) return;
    int v = r0 + rl;
    int ne = (int)degD[v]; if (ne > MAXDEG) ne = MAXDEG;
    const unsigned* erow = ell + (size_t)v * MAXDEG;
    unsigned packed = (lane < ne) ? erow[lane] : 0u;
    unsigned long long vm = __ballot(lane < ne);
    unsigned t_l = packed & 15u;
    unsigned long long m = vm;
#pragma unroll
    for (int b = 0; b < 4; b++) {
        unsigned long long bb = __ballot((t_l >> b) & 1u);
        m &= ((t_l >> b) & 1u) ? bb : ~bb;
    }
    int cnt = __popcll(m); if (cnt < 1) cnt = 1;
    float norm_l = 1.0f / (float)cnt;          // 1/deg(dst, my_type)

    float accx[NBASES], accy[NBASES];
#pragma unroll
    for (int b = 0; b < NBASES; b++) { accx[b] = 0.f; accy[b] = 0.f; }
    const __hip_bfloat162* h2p = (const __hip_bfloat162*)hin;
    for (int e = 0; e < ne; e++) {
        unsigned ed = __shfl(packed, e);       // wave-uniform -> readlane (scalar)
        float nrm = __shfl(norm_l, e);
        int t = (int)(ed & 15u);
        int s = (int)(ed >> 4);
        __hip_bfloat162 xv = h2p[(size_t)s * 64 + lane];
        float xl = __bfloat162float(xv.x), xh = __bfloat162float(xv.y);
#pragma unroll
        for (int b = 0; b < NBASES; b++) {
            float sc = compS[t * NBASES + b] * nrm;
            accx[b] += sc * xl;
            accy[b] += sc * xh;
        }
    }
    __hip_bfloat162* A2 = (__hip_bfloat162*)(A + (size_t)rl * KTOT);
#pragma unroll
    for (int b = 0; b < NBASES; b++) {
        __hip_bfloat162 o;
        o.x = __float2bfloat16(accx[b]);
        o.y = __float2bfloat16(accy[b]);
        A2[b * 64 + lane] = o;
    }
    A2[512 + lane] = h2p[(size_t)v * 64 + lane];   // root part: own features
}

// WT[o][k] (B^T, K-contiguous).
__global__ __launch_bounds__(256)
void k_w(const float* __restrict__ bases, const float* __restrict__ root,
         __hip_bfloat16* __restrict__ WT, int dout, int npad)
{
    int idx = blockIdx.x * 256 + threadIdx.x;
    int total = npad * KTOT;
    if (idx >= total) return;
    int o = idx / KTOT, k = idx - o * KTOT;
    float v = 0.f;
    if (o < dout) v = (k < 1024) ? bases[k * dout + o] : root[(k - 1024) * dout + o];
    WT[idx] = __float2bfloat16(v);
}

// C[M,NT] = A[M,K] * WT[NT,K]^T. 128x{128|64} tile, BK=32, 4 waves,
// mfma_f32_16x16x32_bf16, global_load_lds (width 16) staging.
template<int NT, bool RELU, bool FINAL>
__global__ __launch_bounds__(256)
void k_gemm(const __hip_bfloat16* __restrict__ A,
            const __hip_bfloat16* __restrict__ WT,
            const float* __restrict__ bias,
            void* __restrict__ outp,
            int r0, int rows, int dout)
{
    constexpr int WM = (NT == 128) ? 2 : 4;
    constexpr int WN = 4 / WM;
    constexpr int MT = 128 / (16 * WM);
    constexpr int NTW = NT / (16 * WN);
    __shared__ __align__(16) __hip_bfloat16 As[128 * 32];
    __shared__ __align__(16) __hip_bfloat16 Bs[NT * 32];
    int tid = threadIdx.x;
    int wave = tid >> 6, lane = tid & 63;
    int wm = wave % WM, wn = wave / WM;
    int bm = blockIdx.x * 128;
    int lm = lane & 15, lq = lane >> 4;
    f32x4v zero = {0.f, 0.f, 0.f, 0.f};
    f32x4v acc[MT][NTW];
#pragma unroll
    for (int a = 0; a < MT; a++)
#pragma unroll
        for (int b = 0; b < NTW; b++) acc[a][b] = zero;

    for (int k0 = 0; k0 < KTOT; k0 += 32) {
#pragma unroll
        for (int j = 0; j < 2; j++) {          // A tile 128x32: slot*16B lds-contig
            int slot = tid + 256 * j;
            int row = slot >> 2, kc = (slot & 3) << 3;
            __builtin_amdgcn_global_load_lds(
                (const __attribute__((address_space(1))) void*)
                    &A[(size_t)(bm + row) * KTOT + k0 + kc],
                (__attribute__((address_space(3))) void*)&As[slot * 8],
                16, 0, 0);
        }
#pragma unroll
        for (int j = 0; j < NT / 64; j++) {    // B tile NTx32
            int slot = tid + 256 * j;
            int row = slot >> 2, kc = (slot & 3) << 3;
            __builtin_amdgcn_global_load_lds(
                (const __attribute__((address_space(1))) void*)
                    &WT[(size_t)row * KTOT + k0 + kc],
                (__attribute__((address_space(3))) void*)&Bs[slot * 8],
                16, 0, 0);
        }
        __syncthreads();
        bf16x8v af[MT], bfr[NTW];
#pragma unroll
        for (int mt = 0; mt < MT; mt++)
            af[mt] = *(const bf16x8v*)&As[(wm * (16 * MT) + mt * 16 + lm) * 32 + lq * 8];
#pragma unroll
        for (int nt = 0; nt < NTW; nt++)
            bfr[nt] = *(const bf16x8v*)&Bs[(wn * (16 * NTW) + nt * 16 + lm) * 32 + lq * 8];
#pragma unroll
        for (int mt = 0; mt < MT; mt++)
#pragma unroll
            for (int nt = 0; nt < NTW; nt++)
                acc[mt][nt] = __builtin_amdgcn_mfma_f32_16x16x32_bf16(
                    af[mt], bfr[nt], acc[mt][nt], 0, 0, 0);
        __syncthreads();
    }
#pragma unroll
    for (int mt = 0; mt < MT; mt++) {
        int rbase = bm + wm * (16 * MT) + mt * 16 + lq * 4;
#pragma unroll
        for (int nt = 0; nt < NTW; nt++) {
            int col = wn * (16 * NTW) + nt * 16 + lm;
#pragma unroll
            for (int i = 0; i < 4; i++) {
                int rl = rbase + i;
                if (rl < rows && col < dout) {
                    float v = acc[mt][nt][i] + bias[col];
                    if (RELU) v = fmaxf(v, 0.f);
                    if (FINAL)
                        ((float*)outp)[(size_t)(r0 + rl) * NCLS + col] = v;
                    else
                        ((__hip_bfloat16*)outp)[(size_t)(r0 + rl) * DFEAT + col] =
                            __float2bfloat16(v);
                }
            }
        }
    }
}

extern "C" void kernel_launch(void* const* d_in, const int* in_sizes, int n_in,
                              void* d_out, int out_size, void* d_ws, size_t ws_size,
                              hipStream_t stream)
{
    const float* x  = (const float*)d_in[0];
    const int* esrc = (const int*)d_in[1];
    const int* edst = (const int*)d_in[2];
    const int* etyp = (const int*)d_in[3];
    const float* basesA[3] = {(const float*)d_in[4], (const float*)d_in[8], (const float*)d_in[12]};
    const float* compA[3]  = {(const float*)d_in[5], (const float*)d_in[9], (const float*)d_in[13]};
    const float* rootA[3]  = {(const float*)d_in[6], (const float*)d_in[10], (const float*)d_in[14]};
    const float* biasA[3]  = {(const float*)d_in[7], (const float*)d_in[11], (const float*)d_in[15]};

    size_t off = 0;
    char* base = (char*)d_ws;
    auto carve = [&](size_t bytes) -> void* {
        void* r = base + off;
        off += (bytes + 255) & ~(size_t)255;
        return r;
    };
    __hip_bfloat16* xb = (__hip_bfloat16*)carve((size_t)NNODES * DFEAT * 2);
    __hip_bfloat16* h1 = (__hip_bfloat16*)carve((size_t)NNODES * DFEAT * 2);
    __hip_bfloat16* h2 = (__hip_bfloat16*)carve((size_t)NNODES * DFEAT * 2);
    __hip_bfloat16* WT = (__hip_bfloat16*)carve((size_t)128 * KTOT * 2);
    unsigned* ell  = (unsigned*)carve((size_t)NNODES * MAXDEG * 4);
    unsigned* degD = (unsigned*)carve((size_t)NNODES * 4);

    if (ws_size <= off) return;
    size_t arows = (ws_size - off) / ((size_t)KTOT * 2);
    if (arows > 100096) arows = 100096;
    int chunk = (int)(arows & ~(size_t)127);
    if (chunk < 128) return;
    __hip_bfloat16* A = (__hip_bfloat16*)(base + off);

    hipMemsetAsync(degD, 0, (size_t)NNODES * 4, stream);
    k_convert<<<(NNODES * DFEAT + 255) / 256, 256, 0, stream>>>(x, xb, NNODES * DFEAT);
    k_build<<<(NEDGES + 255) / 256, 256, 0, stream>>>(esrc, edst, etyp, degD, ell);

    const __hip_bfloat16* hin = xb;
    __hip_bfloat16* houts[2] = {h1, h2};
    for (int l = 0; l < 3; l++) {
        int dout = (l == 2) ? NCLS : DFEAT;
        int npad = (l == 2) ? 64 : 128;
        k_w<<<(npad * KTOT + 255) / 256, 256, 0, stream>>>(basesA[l], rootA[l], WT, dout, npad);
        for (int r0 = 0; r0 < NNODES; r0 += chunk) {
            int rows = NNODES - r0; if (rows > chunk) rows = chunk;
            k_agg<<<(rows + 3) / 4, 256, 0, stream>>>(hin, ell, degD, compA[l], A, r0, rows);
            int gm = (rows + 127) / 128;
            if (l < 2)
                k_gemm<128, true, false><<<gm, 256, 0, stream>>>(A, WT, biasA[l], houts[l], r0, rows, dout);
            else
                k_gemm<64, false, true><<<gm, 256, 0, stream>>>(A, WT, biasA[l], d_out, r0, rows, dout);
        }
        if (l < 2) hin = houts[l];
    }
}